// Round 1
// baseline (313.102 us; speedup 1.0000x reference)
//
#include <hip/hip_runtime.h>
#include <hip/hip_bf16.h>

typedef unsigned short u16;
typedef __attribute__((ext_vector_type(8))) short bf16x8;
typedef __attribute__((ext_vector_type(4))) float f32x4;

#define DEVINL __device__ __forceinline__

struct alignas(16) U8 { u16 v[8]; };

// round-to-nearest-even f32 -> bf16 (no NaN handling needed here)
DEVINL u16 f2bf(float f) {
    unsigned int x = __float_as_uint(f);
    unsigned int r = (x + 0x7fffu + ((x >> 16) & 1u)) >> 16;
    return (u16)r;
}

DEVINL void gload_lds16(const void* g, void* l) {
    __builtin_amdgcn_global_load_lds(
        (const __attribute__((address_space(1))) void*)g,
        (__attribute__((address_space(3))) void*)l,
        16, 0, 0);
}

// ---------------------------------------------------------------------------
// f32 -> bf16 conversion, 8 elems/thread
// ---------------------------------------------------------------------------
__global__ __launch_bounds__(256) void cvt_kernel(const float* __restrict__ in,
                                                  u16* __restrict__ out, int n8) {
    int i = blockIdx.x * blockDim.x + threadIdx.x;
    if (i >= n8) return;
    const float4* p = (const float4*)in + (size_t)i * 2;
    float4 a = p[0], b = p[1];
    U8 u;
    u.v[0] = f2bf(a.x); u.v[1] = f2bf(a.y); u.v[2] = f2bf(a.z); u.v[3] = f2bf(a.w);
    u.v[4] = f2bf(b.x); u.v[5] = f2bf(b.y); u.v[6] = f2bf(b.z); u.v[7] = f2bf(b.w);
    *(U8*)(out + (size_t)i * 8) = u;
}

// ---------------------------------------------------------------------------
// h: f32 -> bf16 + rec_stats (mean over rows of |h| > 0.1)
// grid = 128 blocks x 256 thr; block handles 64 rows, thread handles 8 cols
// ---------------------------------------------------------------------------
__global__ __launch_bounds__(256) void cvt_h_rec_kernel(const float* __restrict__ h,
                                                        u16* __restrict__ hbf,
                                                        float* __restrict__ rec_out) {
    int t = threadIdx.x;
    int rb = blockIdx.x;
    float cnt[8] = {0.f, 0.f, 0.f, 0.f, 0.f, 0.f, 0.f, 0.f};
    for (int r = 0; r < 64; ++r) {
        size_t off = ((size_t)(rb * 64 + r)) * 2048 + t * 8;
        float4 a = *(const float4*)(h + off);
        float4 b = *(const float4*)(h + off + 4);
        float vv[8] = {a.x, a.y, a.z, a.w, b.x, b.y, b.z, b.w};
        U8 u;
#pragma unroll
        for (int j = 0; j < 8; ++j) {
            u.v[j] = f2bf(vv[j]);
            cnt[j] += (fabsf(vv[j]) > 0.1f) ? 1.f : 0.f;
        }
        *(U8*)(hbf + off) = u;
    }
#pragma unroll
    for (int j = 0; j < 8; ++j)
        atomicAdd(&rec_out[t * 8 + j], cnt[j] * (1.0f / 8192.0f));
}

// ---------------------------------------------------------------------------
// GEMM core: C[128x128] tile, NT (A row-major [M][K], B row-major [N][K]),
// BK=64, 4 waves (2x2), each wave 64x64 = 4x4 fragments of 16x16x32 bf16 MFMA.
// ---------------------------------------------------------------------------
DEVINL void gemm_seg(const u16* __restrict__ Ag, const u16* __restrict__ Bg,
                     int lda, int ktiles, int bm, int bn, int t,
                     u16* As, u16* Bs, f32x4 (&acc)[4][4]) {
    const int lane = t & 63;
    const int w = t >> 6;
    const int wr = w >> 1, wc = w & 1;

    for (int kt = 0; kt < ktiles; ++kt) {
        __syncthreads();  // previous compute done before overwriting LDS
        const int k0 = kt * 64;
#pragma unroll
        for (int p = 0; p < 4; ++p) {
            int idx = p * 256 + t;
            int row = idx >> 3;          // 8 threads per 64-col row
            int col = (idx & 7) << 3;    // 8 bf16 per thread
            // wave-uniform LDS base; HW scatters lane l at base + l*16
            char* la = (char*)As + ((p * 256 + (w << 6)) << 4);
            char* lb = (char*)Bs + ((p * 256 + (w << 6)) << 4);
            gload_lds16(Ag + (size_t)(bm * 128 + row) * lda + k0 + col, la);
            gload_lds16(Bg + (size_t)(bn * 128 + row) * lda + k0 + col, lb);
        }
        __syncthreads();  // staging visible
#pragma unroll
        for (int ko = 0; ko < 64; ko += 32) {
            bf16x8 af[4], bfr[4];
#pragma unroll
            for (int i = 0; i < 4; ++i)
                af[i] = *(const bf16x8*)(As + ((wr << 6) + i * 16 + (lane & 15)) * 64 +
                                         ko + ((lane >> 4) << 3));
#pragma unroll
            for (int j = 0; j < 4; ++j)
                bfr[j] = *(const bf16x8*)(Bs + ((wc << 6) + j * 16 + (lane & 15)) * 64 +
                                          ko + ((lane >> 4) << 3));
#pragma unroll
            for (int i = 0; i < 4; ++i)
#pragma unroll
                for (int j = 0; j < 4; ++j)
                    acc[i][j] = __builtin_amdgcn_mfma_f32_16x16x32_bf16(
                        af[i], bfr[j], acc[i][j], 0, 0, 0);
        }
    }
}

// ---------------------------------------------------------------------------
// GEMM12: pre = x@W_in.T + h@W_hh.T + b_h ; h_new = relu(pre)
// writes h_new f32 (output), h_new bf16 (ws), act_stats atomics
// ---------------------------------------------------------------------------
__global__ __launch_bounds__(256, 3) void gemm12_kernel(
    const u16* __restrict__ Xbf, const u16* __restrict__ Win,
    const u16* __restrict__ Hbf, const u16* __restrict__ Whh,
    const float* __restrict__ bh,
    float* __restrict__ hnew_f32, u16* __restrict__ hnew_bf,
    float* __restrict__ act_out) {
    __shared__ alignas(16) u16 As[128 * 64];
    __shared__ alignas(16) u16 Bs[128 * 64];
    constexpr int NBN = 16;      // 2048/128
    constexpr int NWG = 64 * 16; // 1024
    int orig = blockIdx.x;
    int wg = (orig & 7) * (NWG / 8) + (orig >> 3);  // XCD-bijective swizzle
    int bm = wg / NBN, bn = wg % NBN;
    int t = threadIdx.x, lane = t & 63, w = t >> 6, wr = w >> 1, wc = w & 1;

    f32x4 acc[4][4];
#pragma unroll
    for (int i = 0; i < 4; ++i)
#pragma unroll
        for (int j = 0; j < 4; ++j) acc[i][j] = (f32x4){0.f, 0.f, 0.f, 0.f};

    gemm_seg(Xbf, Win, 1024, 1024 / 64, bm, bn, t, As, Bs, acc);
    gemm_seg(Hbf, Whh, 2048, 2048 / 64, bm, bn, t, As, Bs, acc);

    const int row0 = bm * 128 + wr * 64;
    const int col0 = bn * 128 + wc * 64;
#pragma unroll
    for (int j = 0; j < 4; ++j) {
        int col = col0 + j * 16 + (lane & 15);
        float bhv = bh[col];
        float csum = 0.f;
#pragma unroll
        for (int i = 0; i < 4; ++i) {
#pragma unroll
            for (int r = 0; r < 4; ++r) {
                int row = row0 + i * 16 + ((lane >> 4) << 2) + r;
                float v = acc[i][j][r] + bhv;
                v = fmaxf(v, 0.f);
                size_t off = (size_t)row * 2048 + col;
                hnew_f32[off] = v;
                hnew_bf[off] = f2bf(v);
                csum += v;
            }
        }
        // reduce over the 4 lane-groups (rows) -> lanes 0..15 hold column sums
        csum += __shfl_xor(csum, 16, 64);
        csum += __shfl_xor(csum, 32, 64);
        if (lane < 16) atomicAdd(&act_out[col], csum * (1.0f / 8192.0f));
    }
}

// ---------------------------------------------------------------------------
// GEMM3: y = h_new@W_out.T + b_out
// ---------------------------------------------------------------------------
__global__ __launch_bounds__(256, 3) void gemm3_kernel(
    const u16* __restrict__ Hn, const u16* __restrict__ Wout,
    const float* __restrict__ bout, float* __restrict__ y) {
    __shared__ alignas(16) u16 As[128 * 64];
    __shared__ alignas(16) u16 Bs[128 * 64];
    constexpr int NBN = 8;      // 1024/128
    constexpr int NWG = 64 * 8; // 512
    int orig = blockIdx.x;
    int wg = (orig & 7) * (NWG / 8) + (orig >> 3);
    int bm = wg / NBN, bn = wg % NBN;
    int t = threadIdx.x, lane = t & 63, w = t >> 6, wr = w >> 1, wc = w & 1;

    f32x4 acc[4][4];
#pragma unroll
    for (int i = 0; i < 4; ++i)
#pragma unroll
        for (int j = 0; j < 4; ++j) acc[i][j] = (f32x4){0.f, 0.f, 0.f, 0.f};

    gemm_seg(Hn, Wout, 2048, 2048 / 64, bm, bn, t, As, Bs, acc);

    const int row0 = bm * 128 + wr * 64;
    const int col0 = bn * 128 + wc * 64;
#pragma unroll
    for (int j = 0; j < 4; ++j) {
        int col = col0 + j * 16 + (lane & 15);
        float bv = bout[col];
#pragma unroll
        for (int i = 0; i < 4; ++i) {
#pragma unroll
            for (int r = 0; r < 4; ++r) {
                int row = row0 + i * 16 + ((lane >> 4) << 2) + r;
                y[(size_t)row * 1024 + col] = acc[i][j][r] + bv;
            }
        }
    }
}

// ---------------------------------------------------------------------------
extern "C" void kernel_launch(void* const* d_in, const int* in_sizes, int n_in,
                              void* d_out, int out_size, void* d_ws, size_t ws_size,
                              hipStream_t stream) {
    const float* x     = (const float*)d_in[0];  // [8192,1024]
    const float* h     = (const float*)d_in[1];  // [8192,2048]
    const float* W_in  = (const float*)d_in[2];  // [2048,1024]
    const float* W_hh  = (const float*)d_in[3];  // [2048,2048]
    const float* b_h   = (const float*)d_in[4];  // [2048]
    const float* W_out = (const float*)d_in[5];  // [1024,2048]
    const float* b_out = (const float*)d_in[6];  // [1024]

    float* out  = (float*)d_out;
    float* y    = out;                              // 8192*1024
    float* hnew = out + 8388608;                    // 8192*2048
    float* act  = out + 8388608 + 16777216;         // 2048
    // rec = act + 2048

    char* ws = (char*)d_ws;
    u16* x_bf    = (u16*)(ws);                          // 16 MB
    u16* h_bf    = (u16*)(ws + (16ull << 20));          // 32 MB
    u16* win_bf  = (u16*)(ws + (48ull << 20));          //  4 MB
    u16* whh_bf  = (u16*)(ws + (52ull << 20));          //  8 MB
    u16* wout_bf = (u16*)(ws + (60ull << 20));          //  4 MB
    u16* hn_bf   = (u16*)(ws + (64ull << 20));          // 32 MB  (total 96 MB)

    // zero act_stats + rec_stats accumulation regions (harness does not re-poison)
    hipMemsetAsync(act, 0, 4096 * sizeof(float), stream);

    cvt_kernel<<<4096, 256, 0, stream>>>(x, x_bf, 8192 * 1024 / 8);
    cvt_kernel<<<1024, 256, 0, stream>>>(W_in, win_bf, 2048 * 1024 / 8);
    cvt_kernel<<<2048, 256, 0, stream>>>(W_hh, whh_bf, 2048 * 2048 / 8);
    cvt_kernel<<<1024, 256, 0, stream>>>(W_out, wout_bf, 1024 * 2048 / 8);
    cvt_h_rec_kernel<<<128, 256, 0, stream>>>(h, h_bf, act + 2048);

    gemm12_kernel<<<1024, 256, 0, stream>>>(x_bf, win_bf, h_bf, whh_bf, b_h,
                                            hnew, hn_bf, act);
    gemm3_kernel<<<512, 256, 0, stream>>>(hn_bf, wout_bf, b_out, y);
}

// Round 4
// 252.978 us; speedup vs baseline: 1.2377x; 1.2377x over previous
//
#include <hip/hip_runtime.h>
#include <hip/hip_bf16.h>

typedef unsigned short u16;
typedef __attribute__((ext_vector_type(8))) short bf16x8;
typedef __attribute__((ext_vector_type(4))) float f32x4;

#define DEVINL __device__ __forceinline__

struct alignas(16) U8 { u16 v[8]; };

DEVINL u16 f2bf(float f) {
    unsigned int x = __float_as_uint(f);
    unsigned int r = (x + 0x7fffu + ((x >> 16) & 1u)) >> 16;
    return (u16)r;
}

DEVINL void gload_lds16(const void* g, void* l) {
    __builtin_amdgcn_global_load_lds(
        (const __attribute__((address_space(1))) void*)g,
        (__attribute__((address_space(3))) void*)l,
        16, 0, 0);
}

// ---------------------------------------------------------------------------
// fused f32 -> bf16 conversion for x, W_in, W_hh, W_out (one launch)
// ---------------------------------------------------------------------------
__global__ __launch_bounds__(256) void cvt4_kernel(
    const float* __restrict__ x, u16* __restrict__ xb,
    const float* __restrict__ wi, u16* __restrict__ wib,
    const float* __restrict__ wh, u16* __restrict__ whb,
    const float* __restrict__ wo, u16* __restrict__ wob) {
    int i = blockIdx.x * 256 + threadIdx.x;
    const float* src; u16* dst; int off;
    if (i < 1048576)       { src = x;  dst = xb;  off = i; }
    else if (i < 1310720)  { src = wi; dst = wib; off = i - 1048576; }
    else if (i < 1835008)  { src = wh; dst = whb; off = i - 1310720; }
    else                   { src = wo; dst = wob; off = i - 1835008; }
    const float4* p = (const float4*)src + (size_t)off * 2;
    float4 a = p[0], b = p[1];
    U8 u;
    u.v[0] = f2bf(a.x); u.v[1] = f2bf(a.y); u.v[2] = f2bf(a.z); u.v[3] = f2bf(a.w);
    u.v[4] = f2bf(b.x); u.v[5] = f2bf(b.y); u.v[6] = f2bf(b.z); u.v[7] = f2bf(b.w);
    *(U8*)(dst + (size_t)off * 8) = u;
}

// ---------------------------------------------------------------------------
// h: f32 -> bf16 + rec_stats
// ---------------------------------------------------------------------------
__global__ __launch_bounds__(256) void cvt_h_rec_kernel(const float* __restrict__ h,
                                                        u16* __restrict__ hbf,
                                                        float* __restrict__ rec_out) {
    int t = threadIdx.x;
    int rb = blockIdx.x;
    float cnt[8] = {0.f, 0.f, 0.f, 0.f, 0.f, 0.f, 0.f, 0.f};
    for (int r = 0; r < 64; ++r) {
        size_t off = ((size_t)(rb * 64 + r)) * 2048 + t * 8;
        float4 a = *(const float4*)(h + off);
        float4 b = *(const float4*)(h + off + 4);
        float vv[8] = {a.x, a.y, a.z, a.w, b.x, b.y, b.z, b.w};
        U8 u;
#pragma unroll
        for (int j = 0; j < 8; ++j) {
            u.v[j] = f2bf(vv[j]);
            cnt[j] += (fabsf(vv[j]) > 0.1f) ? 1.f : 0.f;
        }
        *(U8*)(hbf + off) = u;
    }
#pragma unroll
    for (int j = 0; j < 8; ++j)
        atomicAdd(&rec_out[t * 8 + j], cnt[j] * (1.0f / 8192.0f));
}

// ---------------------------------------------------------------------------
// segment resolution for the concatenated K (tiles 0-15: x/W_in, 16-47: h/W_hh)
// ---------------------------------------------------------------------------
struct Seg { const u16* p; int lda; int k0; };

DEVINL Seg seg_of(const u16* p0, const u16* p1, int kt) {
    Seg s;
    if (kt < 16) { s.p = p0; s.lda = 1024; s.k0 = kt << 6; }
    else         { s.p = p1; s.lda = 2048; s.k0 = (kt - 16) << 6; }
    return s;
}

// ---------------------------------------------------------------------------
// stage one 128-row half-tile set (16 KB) via 2 x global_load_lds(16B)/thread.
// A sets: set0 rows {0-63,128-191}, set1 rows {64-127,192-255}
// B sets: set0 rows {0-31,64-95,128-159,192-223}, set1 = +32
// LDS linear [256][64] u16; swizzle on the GLOBAL source: col8 ^= (row&7).
// ---------------------------------------------------------------------------
DEVINL void stage_set(const u16* __restrict__ p, int lda, int k0, int rbase,
                      u16* ldsOp, int set, int isA, int t, int w) {
#pragma unroll
    for (int l = 0; l < 2; ++l) {
        int idx = (l << 9) + t;
        int r = idx >> 3, c8 = idx & 7;
        int arow = isA ? (((r >> 6) << 7) + (set << 6) + (r & 63))
                       : (((r >> 5) << 6) + (set << 5) + (r & 31));
        const u16* src = p + (size_t)(rbase + arow) * lda + k0 + ((c8 ^ (arow & 7)) << 3);
        int r0 = (l << 6) + (w << 3);   // wave-uniform first set-row of this load
        int drow = isA ? (((r0 >> 6) << 7) + (set << 6) + (r0 & 63))
                       : (((r0 >> 5) << 6) + (set << 5) + (r0 & 31));
        gload_lds16(src, ldsOp + drow * 64);
    }
}

// fragment reads (swizzled): element addr = row*64 + ((kk*4+hi)^(row&7))*8
#define FRAG_A(MQ) do { \
    _Pragma("unroll") for (int i = 0; i < 4; ++i) \
    _Pragma("unroll") for (int kk = 0; kk < 2; ++kk) { \
        int row_ = (wm << 7) + ((MQ) << 6) + (i << 4) + l15; \
        int cb8_ = ((kk << 2) + hi) ^ (row_ & 7); \
        afr[i][kk] = *(const bf16x8*)(rdA + row_ * 64 + (cb8_ << 3)); \
    } } while (0)

#define FRAG_B(NQ) do { \
    _Pragma("unroll") for (int j = 0; j < 2; ++j) \
    _Pragma("unroll") for (int kk = 0; kk < 2; ++kk) { \
        int row_ = (wn << 6) + ((NQ) << 5) + (j << 4) + l15; \
        int cb8_ = ((kk << 2) + hi) ^ (row_ & 7); \
        bfr[j][kk] = *(const bf16x8*)(rdB + row_ * 64 + (cb8_ << 3)); \
    } } while (0)

#define MFMA_Q(MQ, NQ) do { \
    _Pragma("unroll") for (int i = 0; i < 4; ++i) \
    _Pragma("unroll") for (int j = 0; j < 2; ++j) \
    _Pragma("unroll") for (int kk = 0; kk < 2; ++kk) \
        acc[(MQ)*4+i][(NQ)*2+j] = __builtin_amdgcn_mfma_f32_16x16x32_bf16( \
            afr[i][kk], bfr[j][kk], acc[(MQ)*4+i][(NQ)*2+j], 0, 0, 0); \
    } while (0)

#define BARMID() do { \
    asm volatile("s_barrier" ::: "memory"); \
    asm volatile("s_waitcnt lgkmcnt(0)" ::: "memory"); \
    __builtin_amdgcn_sched_barrier(0); \
    __builtin_amdgcn_s_setprio(1); \
    } while (0)

#define BAREND() do { \
    __builtin_amdgcn_s_setprio(0); \
    __builtin_amdgcn_sched_barrier(0); \
    asm volatile("s_barrier" ::: "memory"); \
    } while (0)

#define BAREND_VM() do { \
    __builtin_amdgcn_s_setprio(0); \
    __builtin_amdgcn_sched_barrier(0); \
    asm volatile("s_waitcnt vmcnt(4)" ::: "memory"); \
    asm volatile("s_barrier" ::: "memory"); \
    } while (0)

// ---------------------------------------------------------------------------
// GEMM12, 256x256 tile, 8-wave, 8-phase counted-vmcnt pipeline.
// pre = x@W_in.T + h@W_hh.T + b_h ; h_new = relu(pre); + act stats
// ---------------------------------------------------------------------------
__global__ __launch_bounds__(512, 2) void gemm12_k8(
    const u16* __restrict__ Xbf, const u16* __restrict__ Win,
    const u16* __restrict__ Hbf, const u16* __restrict__ Whh,
    const float* __restrict__ bh,
    float* __restrict__ hnew_f32, u16* __restrict__ hnew_bf,
    float* __restrict__ act_out) {
    __shared__ alignas(16) u16 lds[2][2][16384];  // [buf][A/B][256*64] = 128 KB
    int orig = blockIdx.x;
    int wg = (orig & 7) * 32 + (orig >> 3);       // XCD swizzle (256 % 8 == 0)
    int bm = wg >> 3, bn = wg & 7;                // 32 x 8 blocks
    int t = threadIdx.x, lane = t & 63, w = t >> 6;
    int wm = w >> 2, wn = w & 3;
    int l15 = lane & 15, hi = lane >> 4;
    int rbA = bm << 8, rbB = bn << 8;

    f32x4 acc[8][4];
#pragma unroll
    for (int i = 0; i < 8; ++i)
#pragma unroll
        for (int j = 0; j < 4; ++j) acc[i][j] = (f32x4){0.f, 0.f, 0.f, 0.f};
    bf16x8 afr[4][2], bfr[2][2];

    u16* A0 = &lds[0][0][0]; u16* B0 = &lds[0][1][0];
    u16* A1 = &lds[1][0][0]; u16* B1 = &lds[1][1][0];

    // prologue: tile0 (all 4 sets) + tile1 (A/B set0) = 12 loads; wait to <=4
    {
        Seg a0 = seg_of(Xbf, Hbf, 0), b0 = seg_of(Win, Whh, 0);
        Seg a1 = seg_of(Xbf, Hbf, 1), b1 = seg_of(Win, Whh, 1);
        stage_set(a0.p, a0.lda, a0.k0, rbA, A0, 0, 1, t, w);
        stage_set(b0.p, b0.lda, b0.k0, rbB, B0, 0, 0, t, w);
        stage_set(a0.p, a0.lda, a0.k0, rbA, A0, 1, 1, t, w);
        stage_set(b0.p, b0.lda, b0.k0, rbB, B0, 1, 0, t, w);
        stage_set(a1.p, a1.lda, a1.k0, rbA, A1, 0, 1, t, w);
        stage_set(b1.p, b1.lda, b1.k0, rbB, B1, 0, 0, t, w);
    }
    asm volatile("s_waitcnt vmcnt(4)" ::: "memory");
    asm volatile("s_barrier" ::: "memory");

    for (int it = 0; it < 24; ++it) {
        int tb = it << 1;
        int t2 = tb + 2 < 47 ? tb + 2 : 47;
        int t3 = tb + 3 < 47 ? tb + 3 : 47;
        Seg a1s = seg_of(Xbf, Hbf, tb + 1), b1s = seg_of(Win, Whh, tb + 1);
        Seg a2s = seg_of(Xbf, Hbf, t2),     b2s = seg_of(Win, Whh, t2);
        Seg a3s = seg_of(Xbf, Hbf, t3),     b3s = seg_of(Win, Whh, t3);

        {   // phases 1-4: read buf0 (tile tb)
            const u16* rdA = A0; const u16* rdB = B0;
            // p1: Q(m0,n0); stage A(tile tb+1) set1 -> buf1
            FRAG_A(0); FRAG_B(0);
            stage_set(a1s.p, a1s.lda, a1s.k0, rbA, A1, 1, 1, t, w);
            BARMID(); MFMA_Q(0, 0); BAREND();
            // p2: Q(m0,n1); stage B(tb+1) set1 -> buf1
            FRAG_B(1);
            stage_set(b1s.p, b1s.lda, b1s.k0, rbB, B1, 1, 0, t, w);
            BARMID(); MFMA_Q(0, 1); BAREND();
            // p3: Q(m1,n0); stage A(tb+2) set0 -> buf0
            FRAG_A(1); FRAG_B(0);
            stage_set(a2s.p, a2s.lda, a2s.k0, rbA, A0, 0, 1, t, w);
            BARMID(); MFMA_Q(1, 0); BAREND();
            // p4: Q(m1,n1); stage B(tb+2) set0 -> buf0; vmcnt(4)
            FRAG_B(1);
            stage_set(b2s.p, b2s.lda, b2s.k0, rbB, B0, 0, 0, t, w);
            BARMID(); MFMA_Q(1, 1); BAREND_VM();
        }
        {   // phases 5-8: read buf1 (tile tb+1)
            const u16* rdA = A1; const u16* rdB = B1;
            // p5: stage A(tb+2) set1 -> buf0
            FRAG_A(0); FRAG_B(0);
            stage_set(a2s.p, a2s.lda, a2s.k0, rbA, A0, 1, 1, t, w);
            BARMID(); MFMA_Q(0, 0); BAREND();
            // p6: stage B(tb+2) set1 -> buf0
            FRAG_B(1);
            stage_set(b2s.p, b2s.lda, b2s.k0, rbB, B0, 1, 0, t, w);
            BARMID(); MFMA_Q(0, 1); BAREND();
            // p7: stage A(tb+3) set0 -> buf1
            FRAG_A(1); FRAG_B(0);
            stage_set(a3s.p, a3s.lda, a3s.k0, rbA, A1, 0, 1, t, w);
            BARMID(); MFMA_Q(1, 0); BAREND();
            // p8: stage B(tb+3) set0 -> buf1; vmcnt(4)
            FRAG_B(1);
            stage_set(b3s.p, b3s.lda, b3s.k0, rbB, B1, 0, 0, t, w);
            BARMID(); MFMA_Q(1, 1); BAREND_VM();
        }
    }

    // epilogue: bias + relu + stores + act column sums
    const int row0 = (bm << 8) + (wm << 7);
    const int col0 = (bn << 8) + (wn << 6);
#pragma unroll
    for (int n = 0; n < 4; ++n) {
        int col = col0 + (n << 4) + l15;
        float bhv = bh[col];
        float csum = 0.f;
#pragma unroll
        for (int m = 0; m < 8; ++m) {
#pragma unroll
            for (int r = 0; r < 4; ++r) {
                int row = row0 + (m << 4) + (hi << 2) + r;
                float v = fmaxf(acc[m][n][r] + bhv, 0.f);
                size_t off = (size_t)row * 2048 + col;
                hnew_f32[off] = v;
                hnew_bf[off] = f2bf(v);
                csum += v;
            }
        }
        csum += __shfl_xor(csum, 16, 64);
        csum += __shfl_xor(csum, 32, 64);
        if (lane < 16) atomicAdd(&act_out[col], csum * (1.0f / 8192.0f));
    }
}

// ---------------------------------------------------------------------------
// GEMM3 (unchanged 128^2 structure): y = h_new@W_out.T + b_out
// ---------------------------------------------------------------------------
DEVINL void gemm_seg(const u16* __restrict__ Ag, const u16* __restrict__ Bg,
                     int lda, int ktiles, int bm, int bn, int t,
                     u16* As, u16* Bs, f32x4 (&acc)[4][4]) {
    const int lane = t & 63;
    const int w = t >> 6;
    const int wr = w >> 1, wc = w & 1;

    for (int kt = 0; kt < ktiles; ++kt) {
        __syncthreads();
        const int k0 = kt * 64;
#pragma unroll
        for (int p = 0; p < 4; ++p) {
            int idx = p * 256 + t;
            int row = idx >> 3;
            int col = (idx & 7) << 3;
            char* la = (char*)As + ((p * 256 + (w << 6)) << 4);
            char* lb = (char*)Bs + ((p * 256 + (w << 6)) << 4);
            gload_lds16(Ag + (size_t)(bm * 128 + row) * lda + k0 + col, la);
            gload_lds16(Bg + (size_t)(bn * 128 + row) * lda + k0 + col, lb);
        }
        __syncthreads();
#pragma unroll
        for (int ko = 0; ko < 64; ko += 32) {
            bf16x8 af[4], bfr2[4];
#pragma unroll
            for (int i = 0; i < 4; ++i)
                af[i] = *(const bf16x8*)(As + ((wr << 6) + i * 16 + (lane & 15)) * 64 +
                                         ko + ((lane >> 4) << 3));
#pragma unroll
            for (int j = 0; j < 4; ++j)
                bfr2[j] = *(const bf16x8*)(Bs + ((wc << 6) + j * 16 + (lane & 15)) * 64 +
                                           ko + ((lane >> 4) << 3));
#pragma unroll
            for (int i = 0; i < 4; ++i)
#pragma unroll
                for (int j = 0; j < 4; ++j)
                    acc[i][j] = __builtin_amdgcn_mfma_f32_16x16x32_bf16(
                        af[i], bfr2[j], acc[i][j], 0, 0, 0);
        }
    }
}

__global__ __launch_bounds__(256, 3) void gemm3_kernel(
    const u16* __restrict__ Hn, const u16* __restrict__ Wout,
    const float* __restrict__ bout, float* __restrict__ y) {
    __shared__ alignas(16) u16 As[128 * 64];
    __shared__ alignas(16) u16 Bs[128 * 64];
    constexpr int NBN = 8;
    constexpr int NWG = 64 * 8;
    int orig = blockIdx.x;
    int wg = (orig & 7) * (NWG / 8) + (orig >> 3);
    int bm = wg / NBN, bn = wg % NBN;
    int t = threadIdx.x, lane = t & 63, w = t >> 6, wr = w >> 1, wc = w & 1;

    f32x4 acc[4][4];
#pragma unroll
    for (int i = 0; i < 4; ++i)
#pragma unroll
        for (int j = 0; j < 4; ++j) acc[i][j] = (f32x4){0.f, 0.f, 0.f, 0.f};

    gemm_seg(Hn, Wout, 2048, 2048 / 64, bm, bn, t, As, Bs, acc);

    const int row0 = bm * 128 + wr * 64;
    const int col0 = bn * 128 + wc * 64;
#pragma unroll
    for (int j = 0; j < 4; ++j) {
        int col = col0 + j * 16 + (lane & 15);
        float bv = bout[col];
#pragma unroll
        for (int i = 0; i < 4; ++i) {
#pragma unroll
            for (int r = 0; r < 4; ++r) {
                int row = row0 + i * 16 + ((lane >> 4) << 2) + r;
                y[(size_t)row * 1024 + col] = acc[i][j][r] + bv;
            }
        }
    }
}

// ---------------------------------------------------------------------------
extern "C" void kernel_launch(void* const* d_in, const int* in_sizes, int n_in,
                              void* d_out, int out_size, void* d_ws, size_t ws_size,
                              hipStream_t stream) {
    const float* x     = (const float*)d_in[0];
    const float* h     = (const float*)d_in[1];
    const float* W_in  = (const float*)d_in[2];
    const float* W_hh  = (const float*)d_in[3];
    const float* b_h   = (const float*)d_in[4];
    const float* W_out = (const float*)d_in[5];
    const float* b_out = (const float*)d_in[6];

    float* out  = (float*)d_out;
    float* y    = out;
    float* hnew = out + 8388608;
    float* act  = out + 8388608 + 16777216;

    char* ws = (char*)d_ws;
    u16* x_bf    = (u16*)(ws);
    u16* h_bf    = (u16*)(ws + (16ull << 20));
    u16* win_bf  = (u16*)(ws + (48ull << 20));
    u16* whh_bf  = (u16*)(ws + (52ull << 20));
    u16* wout_bf = (u16*)(ws + (60ull << 20));
    u16* hn_bf   = (u16*)(ws + (64ull << 20));

    hipMemsetAsync(act, 0, 4096 * sizeof(float), stream);

    cvt4_kernel<<<8192, 256, 0, stream>>>(x, x_bf, W_in, win_bf, W_hh, whh_bf,
                                          W_out, wout_bf);
    cvt_h_rec_kernel<<<128, 256, 0, stream>>>(h, h_bf, act + 2048);

    gemm12_k8<<<256, 512, 0, stream>>>(x_bf, win_bf, h_bf, whh_bf, b_h,
                                       hnew, hn_bf, act);
    gemm3_kernel<<<512, 256, 0, stream>>>(hn_bf, wout_bf, b_out, y);
}

// Round 7
// 233.399 us; speedup vs baseline: 1.3415x; 1.0839x over previous
//
#include <hip/hip_runtime.h>
#include <hip/hip_bf16.h>

typedef unsigned short u16;
typedef __attribute__((ext_vector_type(8))) short bf16x8;
typedef __attribute__((ext_vector_type(4))) float f32x4;

#define DEVINL __device__ __forceinline__

struct alignas(16) U8 { u16 v[8]; };

DEVINL u16 f2bf(float f) {
    unsigned int x = __float_as_uint(f);
    unsigned int r = (x + 0x7fffu + ((x >> 16) & 1u)) >> 16;
    return (u16)r;
}

DEVINL void gload_lds16(const void* g, void* l) {
    __builtin_amdgcn_global_load_lds(
        (const __attribute__((address_space(1))) void*)g,
        (__attribute__((address_space(3))) void*)l,
        16, 0, 0);
}

// ---------------------------------------------------------------------------
// fused f32 -> bf16 conversion for x, W_in, W_hh, W_out
// ---------------------------------------------------------------------------
__global__ __launch_bounds__(256) void cvt4_kernel(
    const float* __restrict__ x, u16* __restrict__ xb,
    const float* __restrict__ wi, u16* __restrict__ wib,
    const float* __restrict__ wh, u16* __restrict__ whb,
    const float* __restrict__ wo, u16* __restrict__ wob) {
    int i = blockIdx.x * 256 + threadIdx.x;
    const float* src; u16* dst; int off;
    if (i < 1048576)       { src = x;  dst = xb;  off = i; }
    else if (i < 1310720)  { src = wi; dst = wib; off = i - 1048576; }
    else if (i < 1835008)  { src = wh; dst = whb; off = i - 1310720; }
    else                   { src = wo; dst = wob; off = i - 1835008; }
    const float4* p = (const float4*)src + (size_t)off * 2;
    float4 a = p[0], b = p[1];
    U8 u;
    u.v[0] = f2bf(a.x); u.v[1] = f2bf(a.y); u.v[2] = f2bf(a.z); u.v[3] = f2bf(a.w);
    u.v[4] = f2bf(b.x); u.v[5] = f2bf(b.y); u.v[6] = f2bf(b.z); u.v[7] = f2bf(b.w);
    *(U8*)(dst + (size_t)off * 8) = u;
}

// ---------------------------------------------------------------------------
// h: f32 -> bf16 + rec_stats
// ---------------------------------------------------------------------------
__global__ __launch_bounds__(256) void cvt_h_rec_kernel(const float* __restrict__ h,
                                                        u16* __restrict__ hbf,
                                                        float* __restrict__ rec_out) {
    int t = threadIdx.x;
    int rb = blockIdx.x;
    float cnt[8] = {0.f, 0.f, 0.f, 0.f, 0.f, 0.f, 0.f, 0.f};
    for (int r = 0; r < 64; ++r) {
        size_t off = ((size_t)(rb * 64 + r)) * 2048 + t * 8;
        float4 a = *(const float4*)(h + off);
        float4 b = *(const float4*)(h + off + 4);
        float vv[8] = {a.x, a.y, a.z, a.w, b.x, b.y, b.z, b.w};
        U8 u;
#pragma unroll
        for (int j = 0; j < 8; ++j) {
            u.v[j] = f2bf(vv[j]);
            cnt[j] += (fabsf(vv[j]) > 0.1f) ? 1.f : 0.f;
        }
        *(U8*)(hbf + off) = u;
    }
#pragma unroll
    for (int j = 0; j < 8; ++j)
        atomicAdd(&rec_out[t * 8 + j], cnt[j] * (1.0f / 8192.0f));
}

// ---------------------------------------------------------------------------
// staging helpers with hoisted addressing:
//  src = p + uni(SALU) + lo(invariant VGPR) [+ 128*ld for the 2nd load]
//  dst = wave-uniform LDS base (HW scatters lane i at +i*16B)
// ---------------------------------------------------------------------------
DEVINL void stA(const u16* p, int uni, int lo, int ld, u16* dst, int w) {
    gload_lds16(p + uni + lo, dst + ((w << 3) << 6));
    gload_lds16(p + uni + lo + (ld << 7), dst + ((128 + (w << 3)) << 6));
}
DEVINL void stB(const u16* p, int uni, int lo, int ld, u16* dst, int w) {
    int d0 = ((w >> 2) << 6) + ((w & 3) << 3);
    gload_lds16(p + uni + lo, dst + (d0 << 6));
    gload_lds16(p + uni + lo + (ld << 7), dst + ((128 + d0) << 6));
}

// segment info for concatenated K (tiles 0-15: x/W_in, 16-47: h/W_hh)
struct SegU { const u16* pA; const u16* pB; int uA; int uB; int ld; int loA; int loB; };

DEVINL SegU segu(int kt, const u16* X, const u16* W1, const u16* H, const u16* W2,
                 int rbA, int rbB, int loA1, int loA2, int loB1, int loB2) {
    SegU s;
    if (kt < 16) {
        int k0 = kt << 6;
        s.pA = X; s.pB = W1; s.ld = 1024;
        s.uA = (rbA << 10) + k0; s.uB = (rbB << 10) + k0;
        s.loA = loA1; s.loB = loB1;
    } else {
        int k0 = (kt - 16) << 6;
        s.pA = H; s.pB = W2; s.ld = 2048;
        s.uA = (rbA << 11) + k0; s.uB = (rbB << 11) + k0;
        s.loA = loA2; s.loB = loB2;
    }
    return s;
}

#define STA(S, SET, BUF) stA((S).pA, (S).uA + ((SET) ? ((S).ld << 6) : 0), (S).loA, \
                             (S).ld, Alds + (BUF) * 16384 + (SET) * 4096, w)
#define STB(S, SET, BUF) stB((S).pB, (S).uB + ((SET) ? ((S).ld << 5) : 0), (S).loB, \
                             (S).ld, Blds + (BUF) * 16384 + (SET) * 2048, w)

// fragment reads: single VGPR base + compile-time byte imm (buf/quad/frag folded)
#define FRAG_A(MQ, BUF) do { \
    _Pragma("unroll") for (int i = 0; i < 4; ++i) { \
        afr[i][0] = *(const bf16x8*)(fA0 + (BUF) * 32768 + (MQ) * 8192 + i * 2048); \
        afr[i][1] = *(const bf16x8*)(fA1 + (BUF) * 32768 + (MQ) * 8192 + i * 2048); \
    } } while (0)

#define FRAG_B(NQ, BUF) do { \
    _Pragma("unroll") for (int j = 0; j < 2; ++j) { \
        bfr[j][0] = *(const bf16x8*)(fB0 + (BUF) * 32768 + (NQ) * 4096 + j * 2048); \
        bfr[j][1] = *(const bf16x8*)(fB1 + (BUF) * 32768 + (NQ) * 4096 + j * 2048); \
    } } while (0)

#define MFMA_Q(MQ, NQ) do { \
    _Pragma("unroll") for (int i = 0; i < 4; ++i) \
    _Pragma("unroll") for (int j = 0; j < 2; ++j) \
    _Pragma("unroll") for (int kk = 0; kk < 2; ++kk) \
        acc[(MQ)*4+i][(NQ)*2+j] = __builtin_amdgcn_mfma_f32_16x16x32_bf16( \
            afr[i][kk], bfr[j][kk], acc[(MQ)*4+i][(NQ)*2+j], 0, 0, 0); \
    } while (0)

#define BARMID() do { \
    asm volatile("s_barrier" ::: "memory"); \
    asm volatile("s_waitcnt lgkmcnt(0)" ::: "memory"); \
    __builtin_amdgcn_sched_barrier(0); \
    __builtin_amdgcn_s_setprio(1); \
    } while (0)

#define BAREND() do { \
    __builtin_amdgcn_s_setprio(0); \
    __builtin_amdgcn_sched_barrier(0); \
    asm volatile("s_barrier" ::: "memory"); \
    } while (0)

#define BAREND_VM() do { \
    __builtin_amdgcn_s_setprio(0); \
    __builtin_amdgcn_sched_barrier(0); \
    asm volatile("s_waitcnt vmcnt(4)" ::: "memory"); \
    asm volatile("s_barrier" ::: "memory"); \
    } while (0)

// ---------------------------------------------------------------------------
// GEMM12, 256x256 tile, 8-wave, 8-phase counted-vmcnt pipeline (hoisted addr)
// ---------------------------------------------------------------------------
__global__ __launch_bounds__(512, 2) void gemm12_k8(
    const u16* __restrict__ Xbf, const u16* __restrict__ Win,
    const u16* __restrict__ Hbf, const u16* __restrict__ Whh,
    const float* __restrict__ bh,
    float* __restrict__ hnew_f32, u16* __restrict__ hnew_bf,
    float* __restrict__ act_out) {
    __shared__ alignas(16) u16 lds[4][16384];  // [A0|A1|B0|B1] = 128 KB
    u16* Alds = &lds[0][0];
    u16* Blds = &lds[2][0];
    int orig = blockIdx.x;
    int wg = (orig & 7) * 32 + (orig >> 3);    // XCD swizzle (256 % 8 == 0)
    int bm = wg >> 3, bn = wg & 7;
    int t = threadIdx.x, lane = t & 63, w = t >> 6;
    int wm = w >> 2, wn = w & 3;
    int l15 = lane & 15, hi = lane >> 4;
    int rbA = bm << 8, rbB = bn << 8;

    // invariant staging lane offsets: load0 row r0 = t>>3, col-group c8 = t&7
    int r0 = t >> 3, c8 = t & 7;
    int swz = (c8 ^ (r0 & 7)) << 3;
    int arB0 = ((r0 >> 5) << 6) + (r0 & 31);
    int loA1 = (r0 << 10) + swz, loA2 = (r0 << 11) + swz;
    int loB1 = (arB0 << 10) + swz, loB2 = (arB0 << 11) + swz;

    // fragment base pointers (swizzle term depends only on l15&7)
    int cb0 = (hi ^ (l15 & 7)) << 4;
    int cb1 = ((4 + hi) ^ (l15 & 7)) << 4;
    const char* fA0 = (const char*)(Alds + (((wm << 7) + l15) << 6)) + cb0;
    const char* fA1 = (const char*)(Alds + (((wm << 7) + l15) << 6)) + cb1;
    const char* fB0 = (const char*)(Blds + (((wn << 6) + l15) << 6)) + cb0;
    const char* fB1 = (const char*)(Blds + (((wn << 6) + l15) << 6)) + cb1;

    f32x4 acc[8][4];
#pragma unroll
    for (int i = 0; i < 8; ++i)
#pragma unroll
        for (int j = 0; j < 4; ++j) acc[i][j] = (f32x4){0.f, 0.f, 0.f, 0.f};
    bf16x8 afr[4][2], bfr[2][2];

    // prologue: tile0 all 4 sets + tile1 set0 (A,B) = 12 loads; wait to <=4
    {
        SegU s0 = segu(0, Xbf, Win, Hbf, Whh, rbA, rbB, loA1, loA2, loB1, loB2);
        SegU s1 = segu(1, Xbf, Win, Hbf, Whh, rbA, rbB, loA1, loA2, loB1, loB2);
        STA(s0, 0, 0); STB(s0, 0, 0);
        STA(s0, 1, 0); STB(s0, 1, 0);
        STA(s1, 0, 1); STB(s1, 0, 1);
    }
    asm volatile("s_waitcnt vmcnt(4)" ::: "memory");
    asm volatile("s_barrier" ::: "memory");

    for (int it = 0; it < 24; ++it) {
        int tb = it << 1;
        int t2 = tb + 2 < 47 ? tb + 2 : 47;
        int t3 = tb + 3 < 47 ? tb + 3 : 47;
        SegU s1 = segu(tb + 1, Xbf, Win, Hbf, Whh, rbA, rbB, loA1, loA2, loB1, loB2);
        SegU s2 = segu(t2,     Xbf, Win, Hbf, Whh, rbA, rbB, loA1, loA2, loB1, loB2);
        SegU s3 = segu(t3,     Xbf, Win, Hbf, Whh, rbA, rbB, loA1, loA2, loB1, loB2);

        // phases 1-4: read buf0 (tile tb)
        FRAG_A(0, 0); FRAG_B(0, 0); STA(s1, 1, 1);
        BARMID(); MFMA_Q(0, 0); BAREND();
        FRAG_B(1, 0); STB(s1, 1, 1);
        BARMID(); MFMA_Q(0, 1); BAREND();
        FRAG_A(1, 0); FRAG_B(0, 0); STA(s2, 0, 0);
        BARMID(); MFMA_Q(1, 0); BAREND();
        FRAG_B(1, 0); STB(s2, 0, 0);
        BARMID(); MFMA_Q(1, 1); BAREND_VM();

        // phases 5-8: read buf1 (tile tb+1)
        FRAG_A(0, 1); FRAG_B(0, 1); STA(s2, 1, 0);
        BARMID(); MFMA_Q(0, 0); BAREND();
        FRAG_B(1, 1); STB(s2, 1, 0);
        BARMID(); MFMA_Q(0, 1); BAREND();
        FRAG_A(1, 1); FRAG_B(0, 1); STA(s3, 0, 1);
        BARMID(); MFMA_Q(1, 0); BAREND();
        FRAG_B(1, 1); STB(s3, 0, 1);
        BARMID(); MFMA_Q(1, 1); BAREND_VM();
    }

    // epilogue: bias + relu + stores + act column sums
    const int row0 = (bm << 8) + (wm << 7);
    const int col0 = (bn << 8) + (wn << 6);
#pragma unroll
    for (int n = 0; n < 4; ++n) {
        int col = col0 + (n << 4) + l15;
        float bhv = bh[col];
        float csum = 0.f;
#pragma unroll
        for (int m = 0; m < 8; ++m) {
#pragma unroll
            for (int r = 0; r < 4; ++r) {
                int row = row0 + (m << 4) + (hi << 2) + r;
                float v = fmaxf(acc[m][n][r] + bhv, 0.f);
                size_t off = (size_t)row * 2048 + col;
                hnew_f32[off] = v;
                hnew_bf[off] = f2bf(v);
                csum += v;
            }
        }
        csum += __shfl_xor(csum, 16, 64);
        csum += __shfl_xor(csum, 32, 64);
        if (lane < 16) atomicAdd(&act_out[col], csum * (1.0f / 8192.0f));
    }
}

// ---------------------------------------------------------------------------
// GEMM3: y = h_new@W_out.T + b_out
// 128x128 tile, 4 waves, 2-phase counted dbuf, swizzled, 2 blocks/CU, grid 512
// ---------------------------------------------------------------------------
#define G3STAGE(KT, BUF) do { \
    int ku = (KT) << 6; \
    _Pragma("unroll") for (int l = 0; l < 4; ++l) { \
        gload_lds16(Hn + uA + ku + lo + l * 65536, \
                    Al + (BUF) * 8192 + (((l << 5) + (w << 3)) << 6)); \
        gload_lds16(Wout + uB + ku + lo + l * 65536, \
                    Bl + (BUF) * 8192 + (((l << 5) + (w << 3)) << 6)); \
    } } while (0)

#define G3FRAGS(BUF) do { \
    _Pragma("unroll") for (int i = 0; i < 4; ++i) { \
        afr[i][0] = *(const bf16x8*)(fA0 + (BUF) * 16384 + i * 2048); \
        afr[i][1] = *(const bf16x8*)(fA1 + (BUF) * 16384 + i * 2048); \
        bfr[i][0] = *(const bf16x8*)(fB0 + (BUF) * 16384 + i * 2048); \
        bfr[i][1] = *(const bf16x8*)(fB1 + (BUF) * 16384 + i * 2048); \
    } } while (0)

#define G3MFMA() do { \
    _Pragma("unroll") for (int i = 0; i < 4; ++i) \
    _Pragma("unroll") for (int j = 0; j < 4; ++j) \
    _Pragma("unroll") for (int kk = 0; kk < 2; ++kk) \
        acc[i][j] = __builtin_amdgcn_mfma_f32_16x16x32_bf16( \
            afr[i][kk], bfr[j][kk], acc[i][j], 0, 0, 0); \
    } while (0)

#define G3END() do { \
    asm volatile("s_waitcnt lgkmcnt(0)" ::: "memory"); \
    asm volatile("s_waitcnt vmcnt(0)" ::: "memory"); \
    asm volatile("s_barrier" ::: "memory"); \
    } while (0)

__global__ __launch_bounds__(256, 2) void gemm3_k2(
    const u16* __restrict__ Hn, const u16* __restrict__ Wout,
    const float* __restrict__ bout, float* __restrict__ y) {
    __shared__ alignas(16) u16 lds[4][8192];  // [A0|A1|B0|B1] = 64 KB
    u16* Al = &lds[0][0];
    u16* Bl = &lds[2][0];
    int orig = blockIdx.x;
    int wg = (orig & 7) * 64 + (orig >> 3);   // XCD swizzle (512 % 8 == 0)
    int bm = wg >> 3, bn = wg & 7;            // 64 x 8
    int t = threadIdx.x, lane = t & 63, w = t >> 6, wr = w >> 1, wc = w & 1;
    int l15 = lane & 15, hi = lane >> 4;

    // staging lane offsets (both operands lda=2048)
    int rr = t >> 3, c8 = t & 7;
    int swz = (c8 ^ (rr & 7)) << 3;
    int lo = (rr << 11) + swz;
    int uA = (bm << 7) << 11;   // bm*128*2048
    int uB = (bn << 7) << 11;

    // fragment bases
    int cb0 = (hi ^ (l15 & 7)) << 4;
    int cb1 = ((4 + hi) ^ (l15 & 7)) << 4;
    const char* fA0 = (const char*)(Al + (((wr << 6) + l15) << 6)) + cb0;
    const char* fA1 = (const char*)(Al + (((wr << 6) + l15) << 6)) + cb1;
    const char* fB0 = (const char*)(Bl + (((wc << 6) + l15) << 6)) + cb0;
    const char* fB1 = (const char*)(Bl + (((wc << 6) + l15) << 6)) + cb1;

    f32x4 acc[4][4];
#pragma unroll
    for (int i = 0; i < 4; ++i)
#pragma unroll
        for (int j = 0; j < 4; ++j) acc[i][j] = (f32x4){0.f, 0.f, 0.f, 0.f};
    bf16x8 afr[4][2], bfr[4][2];

    G3STAGE(0, 0);
    asm volatile("s_waitcnt vmcnt(0)" ::: "memory");
    asm volatile("s_barrier" ::: "memory");

    for (int it = 0; it < 16; ++it) {
        int tb = it << 1;
        int t2 = tb + 2 < 31 ? tb + 2 : 31;
        // half A: stage tb+1 -> buf1, compute buf0 (tile tb)
        G3STAGE(tb + 1, 1);
        G3FRAGS(0);
        G3MFMA();
        G3END();
        // half B: stage t2 -> buf0, compute buf1 (tile tb+1)
        G3STAGE(t2, 0);
        G3FRAGS(1);
        G3MFMA();
        G3END();
    }

    const int row0 = (bm << 7) + (wr << 6);
    const int col0 = (bn << 7) + (wc << 6);
#pragma unroll
    for (int j = 0; j < 4; ++j) {
        int col = col0 + (j << 4) + l15;
        float bv = bout[col];
#pragma unroll
        for (int i = 0; i < 4; ++i) {
#pragma unroll
            for (int r = 0; r < 4; ++r) {
                int row = row0 + (i << 4) + (hi << 2) + r;
                y[(size_t)row * 1024 + col] = acc[i][j][r] + bv;
            }
        }
    }
}

// ---------------------------------------------------------------------------
extern "C" void kernel_launch(void* const* d_in, const int* in_sizes, int n_in,
                              void* d_out, int out_size, void* d_ws, size_t ws_size,
                              hipStream_t stream) {
    const float* x     = (const float*)d_in[0];
    const float* h     = (const float*)d_in[1];
    const float* W_in  = (const float*)d_in[2];
    const float* W_hh  = (const float*)d_in[3];
    const float* b_h   = (const float*)d_in[4];
    const float* W_out = (const float*)d_in[5];
    const float* b_out = (const float*)d_in[6];

    float* out  = (float*)d_out;
    float* y    = out;
    float* hnew = out + 8388608;
    float* act  = out + 8388608 + 16777216;

    char* ws = (char*)d_ws;
    u16* x_bf    = (u16*)(ws);
    u16* h_bf    = (u16*)(ws + (16ull << 20));
    u16* win_bf  = (u16*)(ws + (48ull << 20));
    u16* whh_bf  = (u16*)(ws + (52ull << 20));
    u16* wout_bf = (u16*)(ws + (60ull << 20));
    u16* hn_bf   = (u16*)(ws + (64ull << 20));

    hipMemsetAsync(act, 0, 4096 * sizeof(float), stream);

    cvt4_kernel<<<8192, 256, 0, stream>>>(x, x_bf, W_in, win_bf, W_hh, whh_bf,
                                          W_out, wout_bf);
    cvt_h_rec_kernel<<<128, 256, 0, stream>>>(h, h_bf, act + 2048);

    gemm12_k8<<<256, 512, 0, stream>>>(x_bf, win_bf, h_bf, whh_bf, b_h,
                                       hnew, hn_bf, act);
    gemm3_k2<<<512, 256, 0, stream>>>(hn_bf, wout_bf, b_out, y);
}